// Round 9
// baseline (43.471 us; speedup 1.0000x reference)
//
#include <hip/hip_runtime.h>

// RegionLoss v9: persistent double-buffered pipeline, zero loop barriers.
//  - 1024 blocks x 256 thr (4 blocks/CU exact), each walks slabs of 256
//    cells with stride 1024 (3610 slabs total -> 3..4 iters/block)
//  - per slab issue: 32 channel dword loads -> regs, 5 gl16 -> LDS chunk
//    (each wave stages and reads ONLY its own 1216-word chunk -> no
//    cross-wave sharing -> no barriers)
//  - counted s_waitcnt vmcnt(37): slab t's loads complete while slab t+1's
//    37 loads stay in flight (T4 pattern, sched_barrier-pinned, rule #18)
//  - A/B register sets + buf0/buf1 via unroll-by-2 (static indexing, #20)

namespace {

constexpr int kNC = 13;
constexpr int kCh = 32;                   // 19 + kNC channels per anchor
constexpr int kH = 76, kW = 76;
constexpr int kSP = kH * kW;              // 5776
constexpr int kCells = 32 * 5 * kSP;      // 924160
constexpr int kCPS = 256;                 // cells per slab (= block size)
constexpr int kSlabs = kCells / kCPS;     // 3610
constexpr int kGrid = 1024;               // 4 blocks/CU exact
constexpr int kWW = 64 * 19;              // 1216 words: one wave's chunk
constexpr int kTW = kCPS * 19;            // 4864 words per slab buffer

__device__ __forceinline__ void gl16(const float* g, float* l) {
  __builtin_amdgcn_global_load_lds(
      (const __attribute__((address_space(1))) void*)g,
      (__attribute__((address_space(3))) void*)l, 16, 0, 0);
}

// Issue one slab's loads: 32 channel dwords -> ch[], wave chunk -> buf.
__device__ __forceinline__ void issueSlab(int slab, int tid, int lane, int w,
                                          const float* __restrict__ out,
                                          const float* __restrict__ tgt,
                                          float* __restrict__ buf,
                                          float ch[kCh])
{
  const int n = slab * kCPS + tid;
  const int q = n / kSP;                  // b*NA + a (per-lane)
  const int s = n - q * kSP;
  const float* op = out + (size_t)q * kCh * kSP + s;
#pragma unroll
  for (int c = 0; c < kCh; ++c) ch[c] = op[(size_t)c * kSP];
  asm volatile("" :
      "+v"(ch[0]), "+v"(ch[1]), "+v"(ch[2]), "+v"(ch[3]),
      "+v"(ch[4]), "+v"(ch[5]), "+v"(ch[6]), "+v"(ch[7]),
      "+v"(ch[8]), "+v"(ch[9]), "+v"(ch[10]), "+v"(ch[11]),
      "+v"(ch[12]), "+v"(ch[13]), "+v"(ch[14]), "+v"(ch[15]));
  asm volatile("" :
      "+v"(ch[16]), "+v"(ch[17]), "+v"(ch[18]), "+v"(ch[19]),
      "+v"(ch[20]), "+v"(ch[21]), "+v"(ch[22]), "+v"(ch[23]),
      "+v"(ch[24]), "+v"(ch[25]), "+v"(ch[26]), "+v"(ch[27]),
      "+v"(ch[28]), "+v"(ch[29]), "+v"(ch[30]), "+v"(ch[31]));

  // wave w's 1216-word chunk: 304 float4 = 4 full gl16 + 48-lane gl16
  const float* tg = tgt + (size_t)slab * kTW + w * kWW;
  float* lb = buf + w * kWW;
#pragma unroll
  for (int k = 0; k < 4; ++k)
    gl16(tg + (size_t)(k * 64 + lane) * 4, lb + k * 256);
  if (lane < 48)
    gl16(tg + (size_t)(256 + lane) * 4, lb + 1024);
}

// vmcnt(37): all of the PREVIOUS slab's 37 loads retired; the 37 just
// issued may remain in flight.  (rule #18: sched_barrier after the wait)
#define WAIT_PREV() do {                                   \
    __builtin_amdgcn_sched_barrier(0);                     \
    asm volatile("s_waitcnt vmcnt(37)" ::: "memory");      \
    __builtin_amdgcn_sched_barrier(0);                     \
  } while (0)
#define WAIT_ALL() do {                                    \
    __builtin_amdgcn_sched_barrier(0);                     \
    asm volatile("s_waitcnt vmcnt(0)" ::: "memory");       \
    __builtin_amdgcn_sched_barrier(0);                     \
  } while (0)

__device__ __forceinline__ float computeSlab(int slab, int tid,
                                             const float ch[kCh],
                                             const float* __restrict__ tl)
{
  const int n = slab * kCPS + tid;
  const int q = n / kSP;
  const int s = n - q * kSP;
  const int hh = s / kW;
  const float fh = (float)hh;
  const float fw = (float)(s - hh * kW);

  const int rb = tid * 19;                // inside own wave's staged chunk
  const float clsf = tl[rb];
  const bool obj = (clsf != 0.f);

  float tcf = 0.f, lcd = 0.f;
#pragma unroll
  for (int i = 0; i < 9; ++i) {
    float xv = ch[14 + 2 * i];
    float yv = ch[15 + 2 * i];
    if (i == 0) {
      xv = __builtin_amdgcn_rcpf(1.f + __expf(-xv));
      yv = __builtin_amdgcn_rcpf(1.f + __expf(-yv));
    }
    const float gx = tl[rb + 1 + 2 * i];
    const float gy = tl[rb + 2 + 2 * i];
    const float tx = gx - fw;
    const float ty = gy - fh;
    const float dx = tx - (xv + fw);
    const float dy = ty - (yv + fh);
    const float dt = sqrtf(dx * dx + dy * dy);
    if (dt < 30.f) tcf += __expf(2.f - dt * (1.f / 15.f));
    const float ex = xv - tx;
    const float ey = yv - ty;
    lcd += ex * ex + ey * ey;
  }

  const float d = ch[kNC] - tcf * (1.f / 9.f);
  float loss = 0.005f * d * d;            // 0.5*(0.1*(conf-tconf))^2
  if (obj) loss += 0.5f * lcd;

  if (obj) {
    float mx = ch[0];
#pragma unroll
    for (int c = 1; c < kNC; ++c) mx = fmaxf(mx, ch[c]);
    float se = 0.f;
#pragma unroll
    for (int c = 0; c < kNC; ++c) se += __expf(ch[c] - mx);
    const int tc = (int)clsf;
    float sel = 0.f;
#pragma unroll
    for (int c = 0; c < kNC; ++c) sel += (c == tc) ? ch[c] : 0.f;
    loss += -(sel - mx - __logf(se));
  }
  return loss;
}

__global__ __launch_bounds__(256, 4)
void region_loss_v9(const float* __restrict__ out,
                    const float* __restrict__ tgt,
                    double* __restrict__ acc)
{
  __shared__ __align__(16) float buf0[kTW];
  __shared__ __align__(16) float buf1[kTW];
  __shared__ float wsum[4];

  const int tid  = threadIdx.x;
  const int lane = tid & 63;
  const int w    = tid >> 6;

  float chA[kCh], chB[kCh];
  float loss = 0.f;

  int t = blockIdx.x;                     // < 1024 < kSlabs always
  issueSlab(t, tid, lane, w, out, tgt, buf0, chA);

  for (;;) {
    const int t1 = t + kGrid;
    if (t1 < kSlabs) {
      issueSlab(t1, tid, lane, w, out, tgt, buf1, chB);
      WAIT_PREV();
      loss += computeSlab(t, tid, chA, buf0);
      const int t2 = t1 + kGrid;
      if (t2 < kSlabs) {
        issueSlab(t2, tid, lane, w, out, tgt, buf0, chA);
        WAIT_PREV();
        loss += computeSlab(t1, tid, chB, buf1);
        t = t2;
      } else {
        WAIT_ALL();
        loss += computeSlab(t1, tid, chB, buf1);
        break;
      }
    } else {
      WAIT_ALL();
      loss += computeSlab(t, tid, chA, buf0);
      break;
    }
  }

  // ---- reduce: wave shuffle -> LDS -> one atomic/block, spread slots ----
#pragma unroll
  for (int off = 32; off > 0; off >>= 1)
    loss += __shfl_down(loss, off, 64);

  if (lane == 0) wsum[w] = loss;
  __syncthreads();
  if (tid == 0) {
    const float b = wsum[0] + wsum[1] + wsum[2] + wsum[3];
    atomicAdd(&acc[(blockIdx.x & 63) * 8], (double)b);
  }
}

__global__ void finalize_kernel(const double* __restrict__ acc,
                                float* __restrict__ outv)
{
  const int lane = threadIdx.x;
  double v = acc[lane * 8];
#pragma unroll
  for (int off = 32; off > 0; off >>= 1)
    v += __shfl_down(v, off, 64);
  if (lane == 0) outv[0] = (float)v;
}

}  // namespace

extern "C" void kernel_launch(void* const* d_in, const int* in_sizes, int n_in,
                              void* d_out, int out_size, void* d_ws, size_t ws_size,
                              hipStream_t stream) {
  const float* output = (const float*)d_in[0];
  const float* target = (const float*)d_in[1];
  double* acc = (double*)d_ws;

  hipMemsetAsync(acc, 0, 64 * 8 * sizeof(double), stream);

  region_loss_v9<<<kGrid, 256, 0, stream>>>(output, target, acc);
  finalize_kernel<<<1, 64, 0, stream>>>(acc, (float*)d_out);
}